// Round 1
// baseline (162.255 us; speedup 1.0000x reference)
//
#include <hip/hip_runtime.h>
#include <hip/hip_bf16.h>

#define HCH 256      // hidden channels
#define NPN 8192     // person nodes
#define NJN 8192     // job nodes
#define EAE 262144   // applied edges

typedef short s16x8 __attribute__((ext_vector_type(8)));
typedef float f32x4 __attribute__((ext_vector_type(4)));
typedef unsigned short ushortT;

// ---------------- workspace layout (bytes) ----------------
#define WS_DEG_SRC   0          // int[8192]
#define WS_DEG_DST   32768      // int[8192]
#define WS_CUR       65536      // int[8192]
#define WS_OFFS      98304      // int[8193]
#define WS_DIS_SRC   131328     // float[8192]
#define WS_DIS_DST   164096     // float[8192]
#define WS_CSR       196864     // int[262144]
#define WS_XB        1245440    // bf16[8192*256]
#define WS_ZB        5439744    // bf16[8192*256]
#define WS_GB        9634048    // bf16[8192*256]
#define WS_WBT       13828352   // bf16[256*256]

// zero deg_src, deg_dst, cur (contiguous 24576 ints)
__global__ void k_zero(int* p) {
    int i = blockIdx.x * 256 + threadIdx.x;
    p[i] = 0;
}

__global__ void k_count(const int* __restrict__ row, const int* __restrict__ col,
                        int* deg_src, int* deg_dst) {
    int e = blockIdx.x * 256 + threadIdx.x;
    if (e < EAE) {
        atomicAdd(&deg_src[row[e]], 1);
        atomicAdd(&deg_dst[col[e]], 1);
    }
}

__global__ void k_dis(const int* deg_src, const int* deg_dst,
                      float* dis_src, float* dis_dst) {
    int i = blockIdx.x * 256 + threadIdx.x;
    if (i < NPN) {
        int d = deg_src[i];
        dis_src[i] = d > 0 ? rsqrtf((float)d) : 0.f;
    } else {
        int j = i - NPN;
        int d = deg_dst[j];
        dis_dst[j] = d > 0 ? rsqrtf((float)d) : 0.f;
    }
}

// exclusive scan of deg_dst[8192] -> offs[8193]; single block of 256 threads
__global__ void k_scan(const int* __restrict__ deg, int* __restrict__ offs) {
    __shared__ int part[256];
    int t = threadIdx.x;
    int base = t * 32;
    int local[32];
    int s = 0;
#pragma unroll
    for (int i = 0; i < 32; i++) { local[i] = s; s += deg[base + i]; }
    part[t] = s;
    __syncthreads();
    for (int d = 1; d < 256; d <<= 1) {
        int self = part[t];
        int add = (t >= d) ? part[t - d] : 0;
        __syncthreads();
        part[t] = self + add;
        __syncthreads();
    }
    int chunk_excl = (t > 0) ? part[t - 1] : 0;
#pragma unroll
    for (int i = 0; i < 32; i++) offs[base + i] = chunk_excl + local[i];
    if (t == 255) offs[NJN] = part[255];
}

__global__ void k_bucket(const int* __restrict__ row, const int* __restrict__ col,
                         const int* __restrict__ offs, int* cur, int* csr) {
    int e = blockIdx.x * 256 + threadIdx.x;
    if (e < EAE) {
        int c = col[e];
        int p = atomicAdd(&cur[c], 1);
        csr[offs[c] + p] = row[e];
    }
}

// x_person fp32 -> bf16 (2M elems, 4 per thread)
__global__ void k_xb(const float* __restrict__ x, ushortT* __restrict__ xb) {
    int i = (blockIdx.x * 256 + threadIdx.x) * 4;
#pragma unroll
    for (int k = 0; k < 4; k++) {
        __hip_bfloat16 h = __float2bfloat16(x[i + k]);
        xb[i + k] = *reinterpret_cast<ushortT*>(&h);
    }
}

// WbT[n][k] = bf16(W[k][n])
__global__ void k_wbt(const float* __restrict__ W, ushortT* __restrict__ wbt) {
    int idx = blockIdx.x * 256 + threadIdx.x;  // 65536
    int n = idx >> 8, k = idx & 255;
    __hip_bfloat16 h = __float2bfloat16(W[k * HCH + n]);
    wbt[idx] = *reinterpret_cast<ushortT*>(&h);
}

// Z[j][c] = dis_dst[j] * sum_{e in j} dis_src[src_e] * x[src_e][c]  (bf16 out)
__global__ void k_agg(const float* __restrict__ x, const int* __restrict__ csr,
                      const int* __restrict__ offs, const float* __restrict__ dis_src,
                      const float* __restrict__ dis_dst, ushortT* __restrict__ Zb) {
    int j = blockIdx.x;
    int c = threadIdx.x;  // 256
    int e0 = offs[j], e1 = offs[j + 1];
    float acc = 0.f;
    int e = e0;
    for (; e + 1 < e1; e += 2) {
        int s0 = csr[e], s1 = csr[e + 1];
        float w0 = dis_src[s0], w1 = dis_src[s1];
        acc += w0 * x[(size_t)s0 * HCH + c];
        acc += w1 * x[(size_t)s1 * HCH + c];
    }
    if (e < e1) {
        int s0 = csr[e];
        acc += dis_src[s0] * x[(size_t)s0 * HCH + c];
    }
    float z = acc * dis_dst[j];
    __hip_bfloat16 h = __float2bfloat16(z);
    Zb[(size_t)j * HCH + c] = *reinterpret_cast<ushortT*>(&h);
}

// ---------------- GEMM: C = A[M,256] @ Bt[N,256]^T ----------------
// 128x128 tile, 4 waves (2x2 of 64x64), BK=64, XOR-swizzled LDS.
// SIGMOID=true : Cout = float*, sigmoid epilogue
// SIGMOID=false: Cout = bf16*,  += bias[col]
template <bool SIGMOID>
__global__ __launch_bounds__(256, 2)
void k_gemm(const ushortT* __restrict__ A, const ushortT* __restrict__ Bt,
            const float* __restrict__ bias, void* __restrict__ Cout, int Ncols) {
    __shared__ ushortT smA[128 * 64];
    __shared__ ushortT smB[128 * 64];
    int tid = threadIdx.x;
    int wid = tid >> 6, lane = tid & 63;
    int brow = blockIdx.y * 128;
    int bcol = blockIdx.x * 128;
    int wrow = (wid >> 1) * 64;
    int wcol = (wid & 1) * 64;

    f32x4 acc[4][4] = {};

    int lr = lane & 15;
    int kq = lane >> 4;

    for (int k0 = 0; k0 < HCH; k0 += 64) {
        __syncthreads();
        // stage A,B tiles: 128 rows x 64 cols bf16 = 8 chunks of 16B per row
#pragma unroll
        for (int i = 0; i < 4; i++) {
            int cch = tid + i * 256;        // chunk id 0..1023
            int r = cch >> 3, cc = cch & 7; // row, 16B-chunk-in-row
            int byteoff = (r * 128 + cc * 16) ^ ((r & 7) << 4);
            uint4 va = *(const uint4*)(A + (size_t)(brow + r) * HCH + k0 + cc * 8);
            *(uint4*)((char*)smA + byteoff) = va;
            uint4 vb = *(const uint4*)(Bt + (size_t)(bcol + r) * HCH + k0 + cc * 8);
            *(uint4*)((char*)smB + byteoff) = vb;
        }
        __syncthreads();
#pragma unroll
        for (int kk = 0; kk < 64; kk += 32) {
            s16x8 af[4], bfr[4];
            int kbyte = (kk + kq * 8) * 2;
#pragma unroll
            for (int m = 0; m < 4; m++) {
                int r = wrow + m * 16 + lr;
                int byteoff = (r * 128 + kbyte) ^ ((r & 7) << 4);
                af[m] = *(const s16x8*)((const char*)smA + byteoff);
            }
#pragma unroll
            for (int n = 0; n < 4; n++) {
                int r = wcol + n * 16 + lr;
                int byteoff = (r * 128 + kbyte) ^ ((r & 7) << 4);
                bfr[n] = *(const s16x8*)((const char*)smB + byteoff);
            }
#pragma unroll
            for (int m = 0; m < 4; m++)
#pragma unroll
                for (int n = 0; n < 4; n++)
                    acc[m][n] = __builtin_amdgcn_mfma_f32_16x16x32_bf16(
                        af[m], bfr[n], acc[m][n], 0, 0, 0);
        }
    }

    // epilogue: C/D layout col=lane&15, row=(lane>>4)*4+j
    int rq = lane >> 4;
#pragma unroll
    for (int m = 0; m < 4; m++) {
#pragma unroll
        for (int n = 0; n < 4; n++) {
#pragma unroll
            for (int j = 0; j < 4; j++) {
                int gr = brow + wrow + m * 16 + rq * 4 + j;
                int gc = bcol + wcol + n * 16 + lr;
                float v = acc[m][n][j];
                if (SIGMOID) {
                    ((float*)Cout)[(size_t)gr * Ncols + gc] = 1.f / (1.f + __expf(-v));
                } else {
                    v += bias[gc];
                    __hip_bfloat16 h = __float2bfloat16(v);
                    ((ushortT*)Cout)[(size_t)gr * Ncols + gc] =
                        *reinterpret_cast<ushortT*>(&h);
                }
            }
        }
    }
}

extern "C" void kernel_launch(void* const* d_in, const int* in_sizes, int n_in,
                              void* d_out, int out_size, void* d_ws, size_t ws_size,
                              hipStream_t stream) {
    const float* x_person = (const float*)d_in[0];
    const int*   ei_app   = (const int*)d_in[3];   // [2, EA]
    const float* W_aj     = (const float*)d_in[6];
    const float* b_aj     = (const float*)d_in[7];

    const int* erow = ei_app;         // src (person)
    const int* ecol = ei_app + EAE;   // dst (job)

    char* w = (char*)d_ws;
    int*   deg_src = (int*)(w + WS_DEG_SRC);
    int*   deg_dst = (int*)(w + WS_DEG_DST);
    int*   cur     = (int*)(w + WS_CUR);
    int*   offs    = (int*)(w + WS_OFFS);
    float* dis_src = (float*)(w + WS_DIS_SRC);
    float* dis_dst = (float*)(w + WS_DIS_DST);
    int*   csr     = (int*)(w + WS_CSR);
    ushortT* Xb    = (ushortT*)(w + WS_XB);
    ushortT* Zb    = (ushortT*)(w + WS_ZB);
    ushortT* Gb    = (ushortT*)(w + WS_GB);
    ushortT* WbT   = (ushortT*)(w + WS_WBT);

    // 1. zero counters (deg_src, deg_dst, cur are contiguous: 24576 ints)
    k_zero<<<96, 256, 0, stream>>>((int*)w);
    // 2. degree count
    k_count<<<EAE / 256, 256, 0, stream>>>(erow, ecol, deg_src, deg_dst);
    // 3. inverse-sqrt degrees
    k_dis<<<(2 * NPN) / 256, 256, 0, stream>>>(deg_src, deg_dst, dis_src, dis_dst);
    // 4. exclusive scan of deg_dst -> offs
    k_scan<<<1, 256, 0, stream>>>(deg_dst, offs);
    // 5. bucket edges into CSR-by-dst
    k_bucket<<<EAE / 256, 256, 0, stream>>>(erow, ecol, offs, cur, csr);
    // 6. dtype conversions (independent)
    k_xb<<<(NPN * HCH / 4) / 256, 256, 0, stream>>>(x_person, Xb);
    k_wbt<<<(HCH * HCH) / 256, 256, 0, stream>>>(W_aj, WbT);
    // 7. aggregate: Zb[j] = dis_dst[j] * sum dis_src[s] * x[s]
    k_agg<<<NJN, 256, 0, stream>>>(x_person, csr, offs, dis_src, dis_dst, Zb);
    // 8. job_emb (bf16): Gb = Zb @ W + b   [8192,256] @ [256,256]
    {
        dim3 grid(HCH / 128, NJN / 128);
        k_gemm<false><<<grid, 256, 0, stream>>>(Zb, WbT, b_aj, (void*)Gb, HCH);
    }
    // 9. scores = sigmoid(Xb @ Gb^T)   [8192,8192] fp32
    {
        dim3 grid(NJN / 128, NPN / 128);
        k_gemm<true><<<grid, 256, 0, stream>>>(Xb, Gb, nullptr, d_out, NJN);
    }
}

// Round 2
// 154.822 us; speedup vs baseline: 1.0480x; 1.0480x over previous
//
#include <hip/hip_runtime.h>
#include <hip/hip_bf16.h>

#define HCH 256      // hidden channels
#define NPN 8192     // person nodes
#define NJN 8192     // job nodes
#define EAE 262144   // applied edges

typedef _Float16 f16x8 __attribute__((ext_vector_type(8)));
typedef _Float16 f16x4 __attribute__((ext_vector_type(4)));
typedef _Float16 f16x2 __attribute__((ext_vector_type(2)));
typedef float f32x4 __attribute__((ext_vector_type(4)));

// ---------------- workspace layout (bytes) ----------------
#define WS_DEG_SRC   0          // int[8192]
#define WS_DEG_DST   32768      // int[8192]
#define WS_CUR       65536      // int[8192]
#define WS_OFFS      98304      // int[8193]
#define WS_DIS_SRC   131328     // float[8192]
#define WS_DIS_DST   164096     // float[8192]
#define WS_CSR       196864     // int[262144]
#define WS_XH        1245440    // f16[8192*256]
#define WS_ZH        5439744    // f16[8192*256]
#define WS_GH        9634048    // f16[8192*256]
#define WS_WHT       13828352   // f16[256*256]

// zero deg_src, deg_dst, cur (contiguous 24576 ints)
__global__ void k_zero(int* p) {
    int i = blockIdx.x * 256 + threadIdx.x;
    p[i] = 0;
}

__global__ void k_count(const int* __restrict__ row, const int* __restrict__ col,
                        int* deg_src, int* deg_dst) {
    int e = blockIdx.x * 256 + threadIdx.x;
    if (e < EAE) {
        atomicAdd(&deg_src[row[e]], 1);
        atomicAdd(&deg_dst[col[e]], 1);
    }
}

// fused: block 0 -> scan(deg_dst)->offs ; blocks 1..64 -> dis ; 65..320 -> WhT ;
// 321..2368 -> x fp32 -> f16
__global__ void k_prep(const int* __restrict__ deg_src, const int* __restrict__ deg_dst,
                       int* __restrict__ offs, float* __restrict__ dis_src,
                       float* __restrict__ dis_dst, const float* __restrict__ W,
                       _Float16* __restrict__ WhT, const float* __restrict__ x,
                       _Float16* __restrict__ Xh) {
    int bid = blockIdx.x;
    int t = threadIdx.x;
    if (bid == 0) {
        // exclusive scan of deg_dst[8192] -> offs[8193]
        __shared__ int part[256];
        int base = t * 32;
        int local[32];
        int s = 0;
#pragma unroll
        for (int i = 0; i < 32; i++) { local[i] = s; s += deg_dst[base + i]; }
        part[t] = s;
        __syncthreads();
        for (int d = 1; d < 256; d <<= 1) {
            int self = part[t];
            int add = (t >= d) ? part[t - d] : 0;
            __syncthreads();
            part[t] = self + add;
            __syncthreads();
        }
        int chunk_excl = (t > 0) ? part[t - 1] : 0;
#pragma unroll
        for (int i = 0; i < 32; i++) offs[base + i] = chunk_excl + local[i];
        if (t == 255) offs[NJN] = part[255];
    } else if (bid < 65) {
        int i = (bid - 1) * 256 + t;   // 0..16383
        if (i < NPN) {
            int d = deg_src[i];
            dis_src[i] = d > 0 ? rsqrtf((float)d) : 0.f;
        } else {
            int j = i - NPN;
            int d = deg_dst[j];
            dis_dst[j] = d > 0 ? rsqrtf((float)d) : 0.f;
        }
    } else if (bid < 321) {
        int idx = (bid - 65) * 256 + t;  // 65536
        int n = idx >> 8, k = idx & 255;
        WhT[idx] = (_Float16)W[k * HCH + n];
    } else {
        int i = ((bid - 321) * 256 + t) * 4;  // 2M elems, 4/thread
        float4 v = *(const float4*)(x + i);
        f16x4 h;
        h[0] = (_Float16)v.x; h[1] = (_Float16)v.y;
        h[2] = (_Float16)v.z; h[3] = (_Float16)v.w;
        *(f16x4*)(Xh + i) = h;
    }
}

__global__ void k_bucket(const int* __restrict__ row, const int* __restrict__ col,
                         const int* __restrict__ offs, int* cur, int* csr) {
    int e = blockIdx.x * 256 + threadIdx.x;
    if (e < EAE) {
        int c = col[e];
        int p = atomicAdd(&cur[c], 1);
        csr[offs[c] + p] = row[e];
    }
}

// Z[j][:] = dis_dst[j] * sum_{e in j} dis_src[src_e] * Xh[src_e][:]  (f16 in/out)
// 128 threads/block, thread c owns channels 2c,2c+1
__global__ void k_agg(const _Float16* __restrict__ Xh, const int* __restrict__ csr,
                      const int* __restrict__ offs, const float* __restrict__ dis_src,
                      const float* __restrict__ dis_dst, _Float16* __restrict__ Zh) {
    int j = blockIdx.x;
    int c = threadIdx.x;  // 0..127
    int e0 = offs[j], e1 = offs[j + 1];
    float a0 = 0.f, a1 = 0.f;
    int e = e0;
    for (; e + 1 < e1; e += 2) {
        int s0 = csr[e], s1 = csr[e + 1];
        float w0 = dis_src[s0], w1 = dis_src[s1];
        f16x2 v0 = *(const f16x2*)(Xh + (size_t)s0 * HCH + 2 * c);
        f16x2 v1 = *(const f16x2*)(Xh + (size_t)s1 * HCH + 2 * c);
        a0 += w0 * (float)v0[0] + w1 * (float)v1[0];
        a1 += w0 * (float)v0[1] + w1 * (float)v1[1];
    }
    if (e < e1) {
        int s0 = csr[e];
        float w0 = dis_src[s0];
        f16x2 v0 = *(const f16x2*)(Xh + (size_t)s0 * HCH + 2 * c);
        a0 += w0 * (float)v0[0];
        a1 += w0 * (float)v0[1];
    }
    float dd = dis_dst[j];
    f16x2 out;
    out[0] = (_Float16)(a0 * dd);
    out[1] = (_Float16)(a1 * dd);
    *(f16x2*)(Zh + (size_t)j * HCH + 2 * c) = out;
}

// ---------------- GEMM: C = A[M,256] @ Bt[N,256]^T ----------------
// 128x128 tile, 4 waves (2x2 of 64x64), BK=64, XOR-swizzled LDS, f16 MFMA.
// SIGMOID=true : Cout = float*, sigmoid epilogue, XCD-swizzled grid
// SIGMOID=false: Cout = f16*,  += bias[col]
template <bool SIGMOID>
__global__ __launch_bounds__(256, 2)
void k_gemm(const _Float16* __restrict__ A, const _Float16* __restrict__ Bt,
            const float* __restrict__ bias, void* __restrict__ Cout, int Ncols) {
    __shared__ _Float16 smA[128 * 64];
    __shared__ _Float16 smB[128 * 64];
    int tid = threadIdx.x;
    int wid = tid >> 6, lane = tid & 63;

    int bx = blockIdx.x, by = blockIdx.y;
    if (SIGMOID) {
        // bijective XCD swizzle: nwg = 64*64 = 4096, divisible by 8
        int nbx = gridDim.x;
        int lin = by * nbx + bx;
        int chunk = (nbx * gridDim.y) >> 3;
        int swz = (lin & 7) * chunk + (lin >> 3);
        bx = swz % nbx;
        by = swz / nbx;
    }
    int brow = by * 128;
    int bcol = bx * 128;
    int wrow = (wid >> 1) * 64;
    int wcol = (wid & 1) * 64;

    f32x4 acc[4][4] = {};

    int lr = lane & 15;
    int kq = lane >> 4;

    for (int k0 = 0; k0 < HCH; k0 += 64) {
        __syncthreads();
        // stage A,B tiles: 128 rows x 64 cols f16 = 8 chunks of 16B per row
#pragma unroll
        for (int i = 0; i < 4; i++) {
            int cch = tid + i * 256;        // chunk id 0..1023
            int r = cch >> 3, cc = cch & 7; // row, 16B-chunk-in-row
            int byteoff = (r * 128 + cc * 16) ^ ((r & 7) << 4);
            uint4 va = *(const uint4*)(A + (size_t)(brow + r) * HCH + k0 + cc * 8);
            *(uint4*)((char*)smA + byteoff) = va;
            uint4 vb = *(const uint4*)(Bt + (size_t)(bcol + r) * HCH + k0 + cc * 8);
            *(uint4*)((char*)smB + byteoff) = vb;
        }
        __syncthreads();
#pragma unroll
        for (int kk = 0; kk < 64; kk += 32) {
            f16x8 af[4], bfr[4];
            int kbyte = (kk + kq * 8) * 2;
#pragma unroll
            for (int m = 0; m < 4; m++) {
                int r = wrow + m * 16 + lr;
                int byteoff = (r * 128 + kbyte) ^ ((r & 7) << 4);
                af[m] = *(const f16x8*)((const char*)smA + byteoff);
            }
#pragma unroll
            for (int n = 0; n < 4; n++) {
                int r = wcol + n * 16 + lr;
                int byteoff = (r * 128 + kbyte) ^ ((r & 7) << 4);
                bfr[n] = *(const f16x8*)((const char*)smB + byteoff);
            }
#pragma unroll
            for (int m = 0; m < 4; m++)
#pragma unroll
                for (int n = 0; n < 4; n++)
                    acc[m][n] = __builtin_amdgcn_mfma_f32_16x16x32_f16(
                        af[m], bfr[n], acc[m][n], 0, 0, 0);
        }
    }

    // epilogue: C/D layout col=lane&15, row=(lane>>4)*4+j
    int rq = lane >> 4;
#pragma unroll
    for (int m = 0; m < 4; m++) {
#pragma unroll
        for (int n = 0; n < 4; n++) {
#pragma unroll
            for (int j = 0; j < 4; j++) {
                int gr = brow + wrow + m * 16 + rq * 4 + j;
                int gc = bcol + wcol + n * 16 + lr;
                float v = acc[m][n][j];
                if (SIGMOID) {
                    ((float*)Cout)[(size_t)gr * Ncols + gc] = 1.f / (1.f + __expf(-v));
                } else {
                    v += bias[gc];
                    ((_Float16*)Cout)[(size_t)gr * Ncols + gc] = (_Float16)v;
                }
            }
        }
    }
}

extern "C" void kernel_launch(void* const* d_in, const int* in_sizes, int n_in,
                              void* d_out, int out_size, void* d_ws, size_t ws_size,
                              hipStream_t stream) {
    const float* x_person = (const float*)d_in[0];
    const int*   ei_app   = (const int*)d_in[3];   // [2, EA]
    const float* W_aj     = (const float*)d_in[6];
    const float* b_aj     = (const float*)d_in[7];

    const int* erow = ei_app;         // src (person)
    const int* ecol = ei_app + EAE;   // dst (job)

    char* w = (char*)d_ws;
    int*   deg_src = (int*)(w + WS_DEG_SRC);
    int*   deg_dst = (int*)(w + WS_DEG_DST);
    int*   cur     = (int*)(w + WS_CUR);
    int*   offs    = (int*)(w + WS_OFFS);
    float* dis_src = (float*)(w + WS_DIS_SRC);
    float* dis_dst = (float*)(w + WS_DIS_DST);
    int*   csr     = (int*)(w + WS_CSR);
    _Float16* Xh   = (_Float16*)(w + WS_XH);
    _Float16* Zh   = (_Float16*)(w + WS_ZH);
    _Float16* Gh   = (_Float16*)(w + WS_GH);
    _Float16* WhT  = (_Float16*)(w + WS_WHT);

    // 1. zero counters (deg_src, deg_dst, cur are contiguous: 24576 ints)
    k_zero<<<96, 256, 0, stream>>>((int*)w);
    // 2. degree count
    k_count<<<EAE / 256, 256, 0, stream>>>(erow, ecol, deg_src, deg_dst);
    // 3. fused scan + rsqrt-deg + W^T f16 + x f16
    k_prep<<<2369, 256, 0, stream>>>(deg_src, deg_dst, offs, dis_src, dis_dst,
                                     W_aj, WhT, x_person, Xh);
    // 4. bucket edges into CSR-by-dst
    k_bucket<<<EAE / 256, 256, 0, stream>>>(erow, ecol, offs, cur, csr);
    // 5. aggregate: Zh[j] = dis_dst[j] * sum dis_src[s] * Xh[s]
    k_agg<<<NJN, 128, 0, stream>>>(Xh, csr, offs, dis_src, dis_dst, Zh);
    // 6. job_emb (f16): Gh = Zh @ W + b   [8192,256] @ [256,256]
    {
        dim3 grid(HCH / 128, NJN / 128);
        k_gemm<false><<<grid, 256, 0, stream>>>(Zh, WhT, b_aj, (void*)Gh, HCH);
    }
    // 7. scores = sigmoid(Xh @ Gh^T)   [8192,8192] fp32
    {
        dim3 grid(NJN / 128, NPN / 128);
        k_gemm<true><<<grid, 256, 0, stream>>>(Xh, Gh, nullptr, d_out, NJN);
    }
}

// Round 3
// 151.844 us; speedup vs baseline: 1.0686x; 1.0196x over previous
//
#include <hip/hip_runtime.h>
#include <hip/hip_bf16.h>

#define HCH 256      // hidden channels
#define NPN 8192     // person nodes
#define NJN 8192     // job nodes
#define EAE 262144   // applied edges

typedef _Float16 f16x8 __attribute__((ext_vector_type(8)));
typedef _Float16 f16x4 __attribute__((ext_vector_type(4)));
typedef _Float16 f16x2 __attribute__((ext_vector_type(2)));
typedef float f32x4 __attribute__((ext_vector_type(4)));

typedef __attribute__((address_space(1))) void glb_void;
typedef __attribute__((address_space(3))) void lds_void;

// ---------------- workspace layout (bytes) ----------------
#define WS_DEG_SRC   0          // int[8192]
#define WS_DEG_DST   32768      // int[8192]
#define WS_CUR       65536      // int[8192]
#define WS_OFFS      98304      // int[8193]
#define WS_DIS_SRC   131328     // float[8192]
#define WS_DIS_DST   164096     // float[8192]
#define WS_CSR       196864     // int[262144]
#define WS_XH        1245440    // f16[8192*256]
#define WS_ZH        5439744    // f16[8192*256]
#define WS_GH        9634048    // f16[8192*256]
#define WS_WHT       13828352   // f16[256*256]

// zero deg_src, deg_dst, cur (contiguous 24576 ints)
__global__ void k_zero(int* p) {
    int i = blockIdx.x * 256 + threadIdx.x;
    p[i] = 0;
}

__global__ void k_count(const int* __restrict__ row, const int* __restrict__ col,
                        int* deg_src, int* deg_dst) {
    int e = blockIdx.x * 256 + threadIdx.x;
    if (e < EAE) {
        atomicAdd(&deg_src[row[e]], 1);
        atomicAdd(&deg_dst[col[e]], 1);
    }
}

// fused: block 0 -> scan(deg_dst)->offs ; blocks 1..64 -> dis ; 65..320 -> WhT ;
// 321..2368 -> x fp32 -> f16
__global__ void k_prep(const int* __restrict__ deg_src, const int* __restrict__ deg_dst,
                       int* __restrict__ offs, float* __restrict__ dis_src,
                       float* __restrict__ dis_dst, const float* __restrict__ W,
                       _Float16* __restrict__ WhT, const float* __restrict__ x,
                       _Float16* __restrict__ Xh) {
    int bid = blockIdx.x;
    int t = threadIdx.x;
    if (bid == 0) {
        // exclusive scan of deg_dst[8192] -> offs[8193]
        __shared__ int part[256];
        int base = t * 32;
        int local[32];
        int s = 0;
#pragma unroll
        for (int i = 0; i < 32; i++) { local[i] = s; s += deg_dst[base + i]; }
        part[t] = s;
        __syncthreads();
        for (int d = 1; d < 256; d <<= 1) {
            int self = part[t];
            int add = (t >= d) ? part[t - d] : 0;
            __syncthreads();
            part[t] = self + add;
            __syncthreads();
        }
        int chunk_excl = (t > 0) ? part[t - 1] : 0;
#pragma unroll
        for (int i = 0; i < 32; i++) offs[base + i] = chunk_excl + local[i];
        if (t == 255) offs[NJN] = part[255];
    } else if (bid < 65) {
        int i = (bid - 1) * 256 + t;   // 0..16383
        if (i < NPN) {
            int d = deg_src[i];
            dis_src[i] = d > 0 ? rsqrtf((float)d) : 0.f;
        } else {
            int j = i - NPN;
            int d = deg_dst[j];
            dis_dst[j] = d > 0 ? rsqrtf((float)d) : 0.f;
        }
    } else if (bid < 321) {
        int idx = (bid - 65) * 256 + t;  // 65536
        int n = idx >> 8, k = idx & 255;
        WhT[idx] = (_Float16)W[k * HCH + n];
    } else {
        int i = ((bid - 321) * 256 + t) * 4;  // 2M elems, 4/thread
        float4 v = *(const float4*)(x + i);
        f16x4 h;
        h[0] = (_Float16)v.x; h[1] = (_Float16)v.y;
        h[2] = (_Float16)v.z; h[3] = (_Float16)v.w;
        *(f16x4*)(Xh + i) = h;
    }
}

__global__ void k_bucket(const int* __restrict__ row, const int* __restrict__ col,
                         const int* __restrict__ offs, int* cur, int* csr) {
    int e = blockIdx.x * 256 + threadIdx.x;
    if (e < EAE) {
        int c = col[e];
        int p = atomicAdd(&cur[c], 1);
        csr[offs[c] + p] = row[e];
    }
}

// Z[j][:] = dis_dst[j] * sum_{e in j} dis_src[src_e] * Xh[src_e][:]  (f16 in/out)
// 128 threads/block, thread c owns channels 2c,2c+1
__global__ void k_agg(const _Float16* __restrict__ Xh, const int* __restrict__ csr,
                      const int* __restrict__ offs, const float* __restrict__ dis_src,
                      const float* __restrict__ dis_dst, _Float16* __restrict__ Zh) {
    int j = blockIdx.x;
    int c = threadIdx.x;  // 0..127
    int e0 = offs[j], e1 = offs[j + 1];
    float a0 = 0.f, a1 = 0.f;
    int e = e0;
    for (; e + 1 < e1; e += 2) {
        int s0 = csr[e], s1 = csr[e + 1];
        float w0 = dis_src[s0], w1 = dis_src[s1];
        f16x2 v0 = *(const f16x2*)(Xh + (size_t)s0 * HCH + 2 * c);
        f16x2 v1 = *(const f16x2*)(Xh + (size_t)s1 * HCH + 2 * c);
        a0 += w0 * (float)v0[0] + w1 * (float)v1[0];
        a1 += w0 * (float)v0[1] + w1 * (float)v1[1];
    }
    if (e < e1) {
        int s0 = csr[e];
        float w0 = dis_src[s0];
        f16x2 v0 = *(const f16x2*)(Xh + (size_t)s0 * HCH + 2 * c);
        a0 += w0 * (float)v0[0];
        a1 += w0 * (float)v0[1];
    }
    float dd = dis_dst[j];
    f16x2 out;
    out[0] = (_Float16)(a0 * dd);
    out[1] = (_Float16)(a1 * dd);
    *(f16x2*)(Zh + (size_t)j * HCH + 2 * c) = out;
}

// ---------------- GEMM: C = A[M,256] @ Bt[N,256]^T ----------------
// 128x128 tile, 4 waves (2x2 of 64x64), BK=64, f16 MFMA.
// m97 structure: global_load_lds width-16 staging into LINEAR LDS,
// 2 barriers per K-step, ds_read_b128 fragments.
// SIGMOID=true : Cout = float*, sigmoid epilogue (v_rcp), XCD-swizzled grid
// SIGMOID=false: Cout = f16*,  += bias[col]
template <bool SIGMOID>
__global__ __launch_bounds__(256, 3)
void k_gemm(const _Float16* __restrict__ A, const _Float16* __restrict__ Bt,
            const float* __restrict__ bias, void* __restrict__ Cout, int Ncols) {
    __shared__ _Float16 smA[128 * 64];
    __shared__ _Float16 smB[128 * 64];
    int tid = threadIdx.x;
    int wid = tid >> 6, lane = tid & 63;

    int bx = blockIdx.x, by = blockIdx.y;
    if (SIGMOID) {
        // bijective XCD swizzle: nwg = 64*64 = 4096, divisible by 8
        int nbx = gridDim.x;
        int lin = by * nbx + bx;
        int chunk = (nbx * gridDim.y) >> 3;
        int swz = (lin & 7) * chunk + (lin >> 3);
        bx = swz % nbx;
        by = swz / nbx;
    }
    int brow = by * 128;
    int bcol = bx * 128;
    int wrow = (wid >> 1) * 64;
    int wcol = (wid & 1) * 64;

    f32x4 acc[4][4] = {};

    int lr = lane & 15;
    int kq = lane >> 4;

    for (int k0 = 0; k0 < HCH; k0 += 64) {
        if (k0) __syncthreads();   // previous compute done reading LDS
        // stage: 1024 chunks of 16B per tile; wave w, iter i covers chunks
        // [i*256 + w*64, +64). LDS dest = wave-uniform base + lane*16 (HW rule).
#pragma unroll
        for (int i = 0; i < 4; i++) {
            int wc0 = i * 256 + wid * 64;   // wave-uniform first chunk
            int c = wc0 + lane;             // this lane's chunk
            int r = c >> 3, cc = c & 7;     // row, 16B-chunk-in-row
            const char* ga = (const char*)A +
                (size_t)(brow + r) * (HCH * 2) + (size_t)(k0 + cc * 8) * 2;
            const char* gb = (const char*)Bt +
                (size_t)(bcol + r) * (HCH * 2) + (size_t)(k0 + cc * 8) * 2;
            __builtin_amdgcn_global_load_lds(
                (glb_void*)ga, (lds_void*)((char*)smA + wc0 * 16), 16, 0, 0);
            __builtin_amdgcn_global_load_lds(
                (glb_void*)gb, (lds_void*)((char*)smB + wc0 * 16), 16, 0, 0);
        }
        __syncthreads();   // compiler drains vmcnt before s_barrier
#pragma unroll
        for (int kk = 0; kk < 64; kk += 32) {
            f16x8 af[4], bfr[4];
            int kbyte = (kk + kq * 8) * 2;
#pragma unroll
            for (int m = 0; m < 4; m++) {
                int r = wrow + m * 16 + lr;
                af[m] = *(const f16x8*)((const char*)smA + r * 128 + kbyte);
            }
#pragma unroll
            for (int n = 0; n < 4; n++) {
                int r = wcol + n * 16 + lr;
                bfr[n] = *(const f16x8*)((const char*)smB + r * 128 + kbyte);
            }
#pragma unroll
            for (int m = 0; m < 4; m++)
#pragma unroll
                for (int n = 0; n < 4; n++)
                    acc[m][n] = __builtin_amdgcn_mfma_f32_16x16x32_f16(
                        af[m], bfr[n], acc[m][n], 0, 0, 0);
        }
    }

    // epilogue: C/D layout col=lane&15, row=(lane>>4)*4+j
    int rq = lane >> 4;
#pragma unroll
    for (int m = 0; m < 4; m++) {
#pragma unroll
        for (int n = 0; n < 4; n++) {
#pragma unroll
            for (int j = 0; j < 4; j++) {
                int gr = brow + wrow + m * 16 + rq * 4 + j;
                int gc = bcol + wcol + n * 16 + lr;
                float v = acc[m][n][j];
                if (SIGMOID) {
                    float e = __expf(-v);
                    ((float*)Cout)[(size_t)gr * Ncols + gc] =
                        __builtin_amdgcn_rcpf(1.f + e);
                } else {
                    v += bias[gc];
                    ((_Float16*)Cout)[(size_t)gr * Ncols + gc] = (_Float16)v;
                }
            }
        }
    }
}

extern "C" void kernel_launch(void* const* d_in, const int* in_sizes, int n_in,
                              void* d_out, int out_size, void* d_ws, size_t ws_size,
                              hipStream_t stream) {
    const float* x_person = (const float*)d_in[0];
    const int*   ei_app   = (const int*)d_in[3];   // [2, EA]
    const float* W_aj     = (const float*)d_in[6];
    const float* b_aj     = (const float*)d_in[7];

    const int* erow = ei_app;         // src (person)
    const int* ecol = ei_app + EAE;   // dst (job)

    char* w = (char*)d_ws;
    int*   deg_src = (int*)(w + WS_DEG_SRC);
    int*   deg_dst = (int*)(w + WS_DEG_DST);
    int*   cur     = (int*)(w + WS_CUR);
    int*   offs    = (int*)(w + WS_OFFS);
    float* dis_src = (float*)(w + WS_DIS_SRC);
    float* dis_dst = (float*)(w + WS_DIS_DST);
    int*   csr     = (int*)(w + WS_CSR);
    _Float16* Xh   = (_Float16*)(w + WS_XH);
    _Float16* Zh   = (_Float16*)(w + WS_ZH);
    _Float16* Gh   = (_Float16*)(w + WS_GH);
    _Float16* WhT  = (_Float16*)(w + WS_WHT);

    // 1. zero counters (deg_src, deg_dst, cur are contiguous: 24576 ints)
    k_zero<<<96, 256, 0, stream>>>((int*)w);
    // 2. degree count
    k_count<<<EAE / 256, 256, 0, stream>>>(erow, ecol, deg_src, deg_dst);
    // 3. fused scan + rsqrt-deg + W^T f16 + x f16
    k_prep<<<2369, 256, 0, stream>>>(deg_src, deg_dst, offs, dis_src, dis_dst,
                                     W_aj, WhT, x_person, Xh);
    // 4. bucket edges into CSR-by-dst
    k_bucket<<<EAE / 256, 256, 0, stream>>>(erow, ecol, offs, cur, csr);
    // 5. aggregate: Zh[j] = dis_dst[j] * sum dis_src[s] * Xh[s]
    k_agg<<<NJN, 128, 0, stream>>>(Xh, csr, offs, dis_src, dis_dst, Zh);
    // 6. job_emb (f16): Gh = Zh @ W + b   [8192,256] @ [256,256]
    {
        dim3 grid(HCH / 128, NJN / 128);
        k_gemm<false><<<grid, 256, 0, stream>>>(Zh, WhT, b_aj, (void*)Gh, HCH);
    }
    // 7. scores = sigmoid(Xh @ Gh^T)   [8192,8192] fp32
    {
        dim3 grid(NJN / 128, NPN / 128);
        k_gemm<true><<<grid, 256, 0, stream>>>(Xh, Gh, nullptr, d_out, NJN);
    }
}